// Round 1
// baseline (2268.059 us; speedup 1.0000x reference)
//
#include <hip/hip_runtime.h>
#include <hip/hip_bf16.h>

#define S_  30
#define B_  16
#define Hd  400
#define Vv  18000
#define Ll  512
#define Gg  3
#define Tt  10
#define SBn 480
#define KP  448      // K padded to 14*32
#define NPAD_W 2560  // W_ih rows [0,1200) + pad, W_hh rows [1280,2480) + pad
#define NPAD_E 18176 // 71*256

typedef unsigned short u16;
typedef __attribute__((ext_vector_type(8))) short bf8;
typedef __attribute__((ext_vector_type(4))) float f4;

__device__ __forceinline__ u16 f2bf(float f){
  union { __hip_bfloat16 h; u16 u; } c;
  c.h = __float2bfloat16(f);
  return c.u;
}
__device__ __forceinline__ float bf2f(u16 x){
  union { u16 u; __hip_bfloat16 h; } c;
  c.u = x;
  return __bfloat162float(c.h);
}

// ---------------- setup kernels ----------------

__global__ void k_setup_w(const float* __restrict__ Wih, const float* __restrict__ Whh,
                          u16* __restrict__ whi, u16* __restrict__ wlo){
  long total = (long)NPAD_W * KP;
  for (long idx = (long)blockIdx.x*256 + threadIdx.x; idx < total; idx += (long)gridDim.x*256){
    int r = (int)(idx / KP), k = (int)(idx - (long)r*KP);
    float v = 0.f;
    if (k < Hd){
      if (r < 1200) v = Wih[(long)r*Hd + k];
      else if (r >= 1280 && r < 2480) v = Whh[(long)(r-1280)*Hd + k];
    }
    u16 hi = f2bf(v);
    whi[idx] = hi;
    wlo[idx] = f2bf(v - bf2f(hi));
  }
}

__global__ void k_setup_e(const float* __restrict__ emb, u16* __restrict__ ebf){
  long total = (long)NPAD_E * KP;
  for (long idx = (long)blockIdx.x*256 + threadIdx.x; idx < total; idx += (long)gridDim.x*256){
    long r = idx / KP; int k = (int)(idx - r*KP);
    float v = (r < Vv && k < Hd) ? emb[r*Hd + k] : 0.f;
    ebf[idx] = f2bf(v);
  }
}

__global__ void k_setup_xh(const float* __restrict__ ehid, const float* __restrict__ semb,
                           const int* __restrict__ didx, const int* __restrict__ sidx,
                           float* __restrict__ X, float* __restrict__ Hh){
  int m = blockIdx.x, k = threadIdx.x;   // 480 blocks x 448 threads
  int s = m >> 4, b = m & 15;
  float xv = 0.f, hv = 0.f;
  if (k < Hd){
    xv = semb[(long)didx[s]*Hd + k] + semb[(long)sidx[s]*Hd + k];
    hv = ehid[(long)b*Hd + k];
  }
  X [(long)m*KP + k] = xv;
  Hh[(long)m*KP + k] = hv;
}

// ---------------- unified NT GEMM  C[m, seg*n_valid + n] = A_seg[m,:] . B_seg[n,:] ----------------
// A: f32 [480][KP], converted to bf16 hi/lo on the fly (SPLIT) or hi-only.
// B: pre-converted bf16 [rows][KP] (hi + optional lo).
// tiles: BM=32, BN=256, BK=32, 256 threads (4 waves, each wave owns 32x64).

template<bool SPLIT>
__global__ __launch_bounds__(256) void gemm_nt(
    const float* A0, const float* A1,
    const u16* __restrict__ Bhi, const u16* __restrict__ Blo,
    float* __restrict__ C, int seg_tiles, int n_valid, int b_seg_rows, int ldc)
{
  __shared__ u16 As_hi[32*40], As_lo[32*40];      // padded stride 40 (bank spread)
  __shared__ u16 Bs_hi[256*40], Bs_lo[256*40];

  int tid = threadIdx.x;
  int mt = blockIdx.x, yt = blockIdx.y;
  int seg = yt / seg_tiles, nt = yt - seg*seg_tiles;
  const float* A = seg ? A1 : A0;
  int m0 = mt*32;
  long brow0 = (long)seg*b_seg_rows + (long)nt*256;

  int w = tid >> 6, l = tid & 63;
  int lr = l & 15, kg = l >> 4;

  f4 acc[2][4] = {};

  int arow = tid >> 3;            // A stage: 32 rows, 8 thr/row, 4 floats each
  int ac4  = (tid & 7) * 4;
  int br4  = tid >> 2;            // B stage: 64 rows/pass, 4 thr/row, 8 u16 each
  int bc8  = (tid & 3) * 8;

  for (int ks = 0; ks < 14; ++ks){
    int k0 = ks*32;
    __syncthreads();
    // stage A (f32 -> bf16 hi/lo)
    {
      f4 v = *(const f4*)(A + (long)(m0+arow)*KP + k0 + ac4);
      u16 h0=f2bf(v.x), h1=f2bf(v.y), h2=f2bf(v.z), h3=f2bf(v.w);
      *(ushort4*)&As_hi[arow*40 + ac4] = make_ushort4(h0,h1,h2,h3);
      if (SPLIT){
        u16 l0=f2bf(v.x-bf2f(h0)), l1=f2bf(v.y-bf2f(h1)),
            l2=f2bf(v.z-bf2f(h2)), l3=f2bf(v.w-bf2f(h3));
        *(ushort4*)&As_lo[arow*40 + ac4] = make_ushort4(l0,l1,l2,l3);
      }
    }
    // stage B
    #pragma unroll
    for (int p = 0; p < 4; ++p){
      long row = brow0 + p*64 + br4;
      *(uint4*)&Bs_hi[(p*64+br4)*40 + bc8] = *(const uint4*)(Bhi + row*KP + k0 + bc8);
      if (SPLIT)
        *(uint4*)&Bs_lo[(p*64+br4)*40 + bc8] = *(const uint4*)(Blo + row*KP + k0 + bc8);
    }
    __syncthreads();
    // compute
    bf8 ah[2], al[2], bh[4], bl[4];
    #pragma unroll
    for (int i = 0; i < 2; ++i){
      ah[i] = *(const bf8*)&As_hi[(i*16+lr)*40 + kg*8];
      if (SPLIT) al[i] = *(const bf8*)&As_lo[(i*16+lr)*40 + kg*8];
    }
    #pragma unroll
    for (int j = 0; j < 4; ++j){
      int r = w*64 + j*16 + lr;
      bh[j] = *(const bf8*)&Bs_hi[r*40 + kg*8];
      if (SPLIT) bl[j] = *(const bf8*)&Bs_lo[r*40 + kg*8];
    }
    #pragma unroll
    for (int i = 0; i < 2; ++i)
      #pragma unroll
      for (int j = 0; j < 4; ++j){
        acc[i][j] = __builtin_amdgcn_mfma_f32_16x16x32_bf16(ah[i], bh[j], acc[i][j], 0,0,0);
        if (SPLIT){
          acc[i][j] = __builtin_amdgcn_mfma_f32_16x16x32_bf16(ah[i], bl[j], acc[i][j], 0,0,0);
          acc[i][j] = __builtin_amdgcn_mfma_f32_16x16x32_bf16(al[i], bh[j], acc[i][j], 0,0,0);
        }
      }
  }
  // C write: row = m0 + i*16 + kg*4 + r ; col = lr within frag
  #pragma unroll
  for (int i = 0; i < 2; ++i)
    #pragma unroll
    for (int j = 0; j < 4; ++j){
      int nl = nt*256 + w*64 + j*16 + lr;
      if (nl < n_valid){
        long col = (long)seg*n_valid + nl;
        int mrow = m0 + i*16 + kg*4;
        #pragma unroll
        for (int r = 0; r < 4; ++r)
          C[(long)(mrow+r)*ldc + col] = acc[i][j][r];
      }
    }
}

// ---------------- GRU combine ----------------
__global__ void k_combine(const float* __restrict__ Gm, const float* __restrict__ bih,
                          const float* __restrict__ bhh, float* __restrict__ Hh){
  int idx = blockIdx.x*256 + threadIdx.x;
  if (idx >= SBn*Hd) return;
  int m = idx / Hd, j = idx - m*Hd;
  const float* g = Gm + (long)m*2400;
  float ir = g[j]       + bih[j];
  float iz = g[400+j]   + bih[400+j];
  float in_= g[800+j]   + bih[800+j];
  float hr = g[1200+j]  + bhh[j];
  float hz = g[1600+j]  + bhh[400+j];
  float hn = g[2000+j]  + bhh[800+j];
  float r = 1.f/(1.f+expf(-(ir+hr)));
  float z = 1.f/(1.f+expf(-(iz+hz)));
  float n = tanhf(in_ + r*hn);
  float h = Hh[(long)m*KP + j];
  Hh[(long)m*KP + j] = (1.f - z)*n + z*h;
}

// ---------------- attention + p_gen (+gates at t==0), SG=5 slots per block ----------------
#define SG 5
__global__ __launch_bounds__(512) void k_attn(
    const float* __restrict__ Eo, const int* __restrict__ cmask,
    const float* __restrict__ Hh, const float* __restrict__ X,
    const float* __restrict__ wr, const float* __restrict__ wrb,
    const float* __restrict__ wg, const float* __restrict__ wgb,
    float* __restrict__ cprobs, float* __restrict__ pgen,
    float* __restrict__ out_gates, int t)
{
  __shared__ float sh_h[SG][Hd];
  __shared__ float sh_c[SG][Hd];
  __shared__ float sh_p[SG][Ll];
  __shared__ float red[Ll];
  int tid = threadIdx.x;
  int b = blockIdx.y;
  int s0 = blockIdx.x * SG;

  for (int i = tid; i < SG*Hd; i += 512){
    int sg = i / Hd, k = i - sg*Hd;
    int m = (s0+sg)*B_ + b;
    sh_h[sg][k] = Hh[(long)m*KP + k];
  }
  __syncthreads();

  // scores: thread = one l
  const float* erow = Eo + ((long)b*Ll + tid)*Hd;
  float sc[SG];
  #pragma unroll
  for (int sg = 0; sg < SG; ++sg) sc[sg] = 0.f;
  for (int k = 0; k < Hd; k += 4){
    f4 e = *(const f4*)&erow[k];
    #pragma unroll
    for (int sg = 0; sg < SG; ++sg)
      sc[sg] += e.x*sh_h[sg][k] + e.y*sh_h[sg][k+1] + e.z*sh_h[sg][k+2] + e.w*sh_h[sg][k+3];
  }
  bool mok = cmask[b*Ll + tid] != 0;

  for (int sg = 0; sg < SG; ++sg){
    float v = mok ? sc[sg] : -__builtin_inff();
    red[tid] = v; __syncthreads();
    for (int o = 256; o > 0; o >>= 1){ if (tid < o) red[tid] = fmaxf(red[tid], red[tid+o]); __syncthreads(); }
    float mx = red[0]; __syncthreads();
    float p = expf(v - mx);
    red[tid] = p; __syncthreads();
    for (int o = 256; o > 0; o >>= 1){ if (tid < o) red[tid] += red[tid+o]; __syncthreads(); }
    float sum = red[0]; __syncthreads();
    p = p / sum;
    sh_p[sg][tid] = p;
    int m = (s0+sg)*B_ + b;
    cprobs[(long)m*Ll + tid] = p;
  }
  __syncthreads();

  // context vector: thread = one k (<400)
  if (tid < Hd){
    float c[SG];
    #pragma unroll
    for (int sg = 0; sg < SG; ++sg) c[sg] = 0.f;
    for (int l2 = 0; l2 < Ll; ++l2){
      float e = Eo[((long)b*Ll + l2)*Hd + tid];
      #pragma unroll
      for (int sg = 0; sg < SG; ++sg) c[sg] += sh_p[sg][l2]*e;
    }
    for (int sg = 0; sg < SG; ++sg) sh_c[sg][tid] = c[sg];
  }
  __syncthreads();

  // p_gen = sigmoid([h, c, x] . wr + b)
  for (int sg = 0; sg < SG; ++sg){
    int m = (s0+sg)*B_ + b;
    float part = 0.f;
    for (int j = tid; j < 1200; j += 512){
      float xv;
      if (j < 400)      xv = sh_h[sg][j];
      else if (j < 800) xv = sh_c[sg][j-400];
      else              xv = X[(long)m*KP + (j-800)];
      part += xv * wr[j];
    }
    red[tid] = part; __syncthreads();
    for (int o = 256; o > 0; o >>= 1){ if (tid < o) red[tid] += red[tid+o]; __syncthreads(); }
    if (tid == 0){
      float x = red[0] + wrb[0];
      pgen[m] = 1.f/(1.f+expf(-x));
    }
    __syncthreads();
  }

  if (t == 0){
    for (int sg = 0; sg < SG; ++sg)
      for (int g = 0; g < Gg; ++g){
        float part = 0.f;
        for (int k = tid; k < Hd; k += 512) part += sh_c[sg][k]*wg[g*Hd + k];
        red[tid] = part; __syncthreads();
        for (int o = 256; o > 0; o >>= 1){ if (tid < o) red[tid] += red[tid+o]; __syncthreads(); }
        if (tid == 0) out_gates[((long)b*S_ + (s0+sg))*Gg + g] = red[0] + wgb[g];
        __syncthreads();
      }
  }
}

// ---------------- vocab softmax reduce (max, sum, argmax of z) ----------------
__global__ __launch_bounds__(256) void k_vreduce(const float* __restrict__ Z,
                                                 float* __restrict__ rmax, float* __restrict__ rsum,
                                                 int* __restrict__ zidx){
  int m = blockIdx.x, tid = threadIdx.x;
  const float* z = Z + (long)m*Vv;
  float mx = -__builtin_inff(); int mi = Vv; float sum = 0.f;
  for (int n = tid; n < Vv; n += 256){
    float v = z[n];
    if (v > mx){ sum = sum*expf(mx - v) + 1.f; mx = v; mi = n; }
    else sum += expf(v - mx);
  }
  __shared__ float smx[256]; __shared__ int sid[256]; __shared__ float ssum[256];
  smx[tid] = mx; sid[tid] = mi; __syncthreads();
  for (int o = 128; o > 0; o >>= 1){
    if (tid < o){
      float v2 = smx[tid+o]; int i2 = sid[tid+o];
      if (v2 > smx[tid] || (v2 == smx[tid] && i2 < sid[tid])){ smx[tid] = v2; sid[tid] = i2; }
    }
    __syncthreads();
  }
  float gmx = smx[0]; int gidx = sid[0];
  ssum[tid] = sum * expf(mx - gmx); __syncthreads();
  for (int o = 128; o > 0; o >>= 1){ if (tid < o) ssum[tid] += ssum[tid+o]; __syncthreads(); }
  if (tid == 0){ rmax[m] = gmx; rsum[m] = ssum[0]; zidx[m] = gidx; }
}

// ---------------- write p_gen * p_vocab to out ----------------
__global__ void k_finalize(const float* __restrict__ Z, const float* __restrict__ rmax,
                           const float* __restrict__ rsum, const float* __restrict__ pgen,
                           float* __restrict__ out, int t){
  int m = blockIdx.y;
  int n = blockIdx.x*256 + threadIdx.x;
  if (n >= Vv) return;
  float e = expf(Z[(long)m*Vv + n] - rmax[m]);
  float pv = e / rsum[m];
  int s = m >> 4, b = m & 15;
  long off = ((long)(b*S_ + s)*Tt + t)*Vv + n;
  out[off] = pgen[m] * pv;
}

// ---------------- scatter copy distribution into out ----------------
__global__ __launch_bounds__(512) void k_scatter(const float* __restrict__ cprobs,
                                                 const float* __restrict__ pgen,
                                                 const int* __restrict__ cidx, const int* __restrict__ cmask,
                                                 float* __restrict__ out, int t){
  int m = blockIdx.x, l = threadIdx.x;
  int b = m & 15, s = m >> 4;
  if (!cmask[b*Ll + l]) return;
  float v = (1.f - pgen[m]) * cprobs[(long)m*Ll + l];
  int tok = cidx[b*Ll + l];
  long off = ((long)(b*S_ + s)*Tt + t)*Vv + tok;
  atomicAdd(&out[off], v);
}

// ---------------- argmax over p_final + greedy feedback ----------------
__global__ __launch_bounds__(512) void k_argfb(const float* __restrict__ out,
                                               const int* __restrict__ cidx,
                                               const float* __restrict__ pgen, const float* __restrict__ rsum,
                                               const int* __restrict__ zidx,
                                               const float* __restrict__ emb, float* __restrict__ X, int t){
  __shared__ float rv[Ll]; __shared__ int ri[Ll];
  int m = blockIdx.x, tid = threadIdx.x;
  int b = m & 15, s = m >> 4;
  long base = ((long)(b*S_ + s)*Tt + t)*Vv;
  int tok = cidx[b*Ll + tid];
  float v = out[base + tok]; int idx = tok;      // true p_final values at ctx tokens
  if (tid == 0){
    float v0 = pgen[m]*(1.f/rsum[m]);            // true p_final at zidx (pre-scatter)
    int i0 = zidx[m];
    if (v0 > v || (v0 == v && i0 < idx)){ v = v0; idx = i0; }
  }
  rv[tid] = v; ri[tid] = idx; __syncthreads();
  for (int o = 256; o > 0; o >>= 1){
    if (tid < o){
      float v2 = rv[tid+o]; int i2 = ri[tid+o];
      if (v2 > rv[tid] || (v2 == rv[tid] && i2 < ri[tid])){ rv[tid] = v2; ri[tid] = i2; }
    }
    __syncthreads();
  }
  int win = ri[0];
  if (tid < Hd) X[(long)m*KP + tid] = emb[(long)win*Hd + tid];
}

// ---------------- launcher ----------------
extern "C" void kernel_launch(void* const* d_in, const int* in_sizes, int n_in,
                              void* d_out, int out_size, void* d_ws, size_t ws_size,
                              hipStream_t stream)
{
  const float* ehid  = (const float*)d_in[0];
  const float* eout  = (const float*)d_in[1];
  const int*   cidx  = (const int*)d_in[2];
  const int*   cmask = (const int*)d_in[3];
  const float* emb   = (const float*)d_in[5];
  const float* semb  = (const float*)d_in[6];
  const int*   didx  = (const int*)d_in[7];
  const int*   sidx  = (const int*)d_in[8];
  const float* Wih   = (const float*)d_in[9];
  const float* Whh   = (const float*)d_in[10];
  const float* bih   = (const float*)d_in[11];
  const float* bhh   = (const float*)d_in[12];
  const float* wr    = (const float*)d_in[13];
  const float* wrb   = (const float*)d_in[14];
  const float* wg    = (const float*)d_in[15];
  const float* wgb   = (const float*)d_in[16];
  float* out = (float*)d_out;

  char* ws = (char*)d_ws;
  u16*   ws_hi = (u16*)(ws + 0);            // 2,293,760
  u16*   ws_lo = (u16*)(ws + 2293760);      // 2,293,760
  u16*   ebf   = (u16*)(ws + 4587520);      // 16,285,696
  float* X     = (float*)(ws + 20873216);   // 860,160
  float* Hh    = (float*)(ws + 21733376);   // 860,160
  float* Gm    = (float*)(ws + 22593536);   // 4,608,000
  float* Z     = (float*)(ws + 27201536);   // 34,560,000
  float* cp    = (float*)(ws + 61761536);   // 983,040
  float* pg    = (float*)(ws + 62744576);   // 2048
  float* rmax  = (float*)(ws + 62746624);   // 2048
  float* rsum  = (float*)(ws + 62748672);   // 2048
  int*   zidx  = (int*)  (ws + 62750720);   // 2048
  float* og = out + (long)B_*S_*Tt*Vv;

  k_setup_w <<<4480, 256, 0, stream>>>(Wih, Whh, ws_hi, ws_lo);
  k_setup_e <<<4096, 256, 0, stream>>>(emb, ebf);
  k_setup_xh<<<480, 448, 0, stream>>>(ehid, semb, didx, sidx, X, Hh);

  for (int t = 0; t < Tt; ++t){
    gemm_nt<true> <<<dim3(15,10), 256, 0, stream>>>(X, Hh, ws_hi, ws_lo, Gm, 5, 1200, 1280, 2400);
    k_combine     <<<750, 256, 0, stream>>>(Gm, bih, bhh, Hh);
    k_attn        <<<dim3(6,16), 512, 0, stream>>>(eout, cmask, Hh, X, wr, wrb, wg, wgb, cp, pg, og, t);
    gemm_nt<false><<<dim3(15,71), 256, 0, stream>>>(Hh, Hh, ebf, ebf, Z, 71, 18000, 0, 18000);
    k_vreduce     <<<480, 256, 0, stream>>>(Z, rmax, rsum, zidx);
    k_finalize    <<<dim3(71,480), 256, 0, stream>>>(Z, rmax, rsum, pg, out, t);
    k_scatter     <<<480, 512, 0, stream>>>(cp, pg, cidx, cmask, out, t);
    k_argfb       <<<480, 512, 0, stream>>>(out, cidx, pg, rsum, zidx, emb, X, t);
  }
}

// Round 2
// 1803.412 us; speedup vs baseline: 1.2576x; 1.2576x over previous
//
#include <hip/hip_runtime.h>
#include <hip/hip_bf16.h>

#define S_  30
#define B_  16
#define Hd  400
#define Vv  18000
#define Ll  512
#define Gg  3
#define Tt  10
#define SBn 480
#define KP  448      // K padded to 14*32
#define NPAD_W 2560  // W_ih rows [0,1280) (1200 valid), W_hh rows [1280,2560) (2480 valid)
#define NPAD_E 18176
#define NST 141      // vocab N-stripes of 128 (141*128 = 18048 >= 18000)
#define SG  5

typedef unsigned short u16;
typedef __attribute__((ext_vector_type(8))) short bf8;
typedef __attribute__((ext_vector_type(4))) float f4;

#define INF __builtin_inff()

__device__ __forceinline__ u16 f2bf(float f){
  union { __hip_bfloat16 h; u16 u; } c;
  c.h = __float2bfloat16(f);
  return c.u;
}
__device__ __forceinline__ float bf2f(u16 x){
  union { u16 u; __hip_bfloat16 h; } c;
  c.u = x;
  return __bfloat162float(c.h);
}

// ---------------- setup kernels ----------------

__global__ void k_setup_w(const float* __restrict__ Wih, const float* __restrict__ Whh,
                          u16* __restrict__ whi, u16* __restrict__ wlo){
  long total = (long)NPAD_W * KP;
  for (long idx = (long)blockIdx.x*256 + threadIdx.x; idx < total; idx += (long)gridDim.x*256){
    int r = (int)(idx / KP), k = (int)(idx - (long)r*KP);
    float v = 0.f;
    if (k < Hd){
      if (r < 1200) v = Wih[(long)r*Hd + k];
      else if (r >= 1280 && r < 2480) v = Whh[(long)(r-1280)*Hd + k];
    }
    u16 hi = f2bf(v);
    whi[idx] = hi;
    wlo[idx] = f2bf(v - bf2f(hi));
  }
}

__global__ void k_setup_e(const float* __restrict__ emb, u16* __restrict__ ebf){
  long total = (long)NPAD_E * KP;
  for (long idx = (long)blockIdx.x*256 + threadIdx.x; idx < total; idx += (long)gridDim.x*256){
    long r = idx / KP; int k = (int)(idx - r*KP);
    float v = (r < Vv && k < Hd) ? emb[r*Hd + k] : 0.f;
    ebf[idx] = f2bf(v);
  }
}

__global__ void k_setup_xh(const float* __restrict__ ehid, const float* __restrict__ semb,
                           const int* __restrict__ didx, const int* __restrict__ sidx,
                           float* __restrict__ X, float* __restrict__ Hh, u16* __restrict__ Hbf){
  int m = blockIdx.x, k = threadIdx.x;   // 480 blocks x 448 threads
  int s = m >> 4, b = m & 15;
  float xv = 0.f, hv = 0.f;
  if (k < Hd){
    xv = semb[(long)didx[s]*Hd + k] + semb[(long)sidx[s]*Hd + k];
    hv = ehid[(long)b*Hd + k];
  }
  X [(long)m*KP + k] = xv;
  Hh[(long)m*KP + k] = hv;
  Hbf[(long)m*KP + k] = 0;   // cols >=400 stay 0 forever; <400 overwritten by k_attn
}

// ---------------- GRU GEMM: Gm[m, seg*1200+n] = A_seg[m,:] . W_seg[n,:]  (split bf16, 3 MFMAs) ----
// grid (15, 20): x = m-tile(32), y: 0..9 -> seg0 (A=X, W_ih), 10..19 -> seg1 (A=Hh, W_hh). BN=128.
__global__ __launch_bounds__(256) void k_ggemm(
    const float* __restrict__ X, const float* __restrict__ Hh,
    const u16* __restrict__ Bhi, const u16* __restrict__ Blo,
    float* __restrict__ Gm)
{
  __shared__ u16 As_hi[32*40], As_lo[32*40];
  __shared__ u16 Bs_hi[128*40], Bs_lo[128*40];
  int tid = threadIdx.x;
  int mt = blockIdx.x, yt = blockIdx.y;
  int seg = yt >= 10 ? 1 : 0, nt = seg ? yt-10 : yt;
  const float* A = seg ? Hh : X;
  int m0 = mt*32;
  long brow0 = (long)seg*1280 + (long)nt*128;
  int w = tid>>6, l = tid&63, lr = l&15, kg = l>>4;
  f4 acc[2][2] = {};
  int arow = tid>>3, ac4 = (tid&7)*4;
  int br4 = tid>>2, bc8 = (tid&3)*8;
  for (int ks = 0; ks < 14; ++ks){
    int k0 = ks*32;
    __syncthreads();
    { f4 v = *(const f4*)(A + (long)(m0+arow)*KP + k0 + ac4);
      u16 h0=f2bf(v.x),h1=f2bf(v.y),h2=f2bf(v.z),h3=f2bf(v.w);
      *(ushort4*)&As_hi[arow*40+ac4] = make_ushort4(h0,h1,h2,h3);
      u16 q0=f2bf(v.x-bf2f(h0)),q1=f2bf(v.y-bf2f(h1)),q2=f2bf(v.z-bf2f(h2)),q3=f2bf(v.w-bf2f(h3));
      *(ushort4*)&As_lo[arow*40+ac4] = make_ushort4(q0,q1,q2,q3);
    }
    #pragma unroll
    for (int p = 0; p < 2; ++p){
      long row = brow0 + p*64 + br4;
      *(uint4*)&Bs_hi[(p*64+br4)*40+bc8] = *(const uint4*)(Bhi + row*KP + k0 + bc8);
      *(uint4*)&Bs_lo[(p*64+br4)*40+bc8] = *(const uint4*)(Blo + row*KP + k0 + bc8);
    }
    __syncthreads();
    bf8 ah[2], al[2], bh[2], bl[2];
    #pragma unroll
    for (int i = 0; i < 2; ++i){
      ah[i] = *(const bf8*)&As_hi[(i*16+lr)*40 + kg*8];
      al[i] = *(const bf8*)&As_lo[(i*16+lr)*40 + kg*8];
    }
    #pragma unroll
    for (int j = 0; j < 2; ++j){
      int r = w*32 + j*16 + lr;
      bh[j] = *(const bf8*)&Bs_hi[r*40 + kg*8];
      bl[j] = *(const bf8*)&Bs_lo[r*40 + kg*8];
    }
    #pragma unroll
    for (int i = 0; i < 2; ++i)
      #pragma unroll
      for (int j = 0; j < 2; ++j){
        acc[i][j] = __builtin_amdgcn_mfma_f32_16x16x32_bf16(ah[i], bh[j], acc[i][j], 0,0,0);
        acc[i][j] = __builtin_amdgcn_mfma_f32_16x16x32_bf16(ah[i], bl[j], acc[i][j], 0,0,0);
        acc[i][j] = __builtin_amdgcn_mfma_f32_16x16x32_bf16(al[i], bh[j], acc[i][j], 0,0,0);
      }
  }
  #pragma unroll
  for (int i = 0; i < 2; ++i)
    #pragma unroll
    for (int j = 0; j < 2; ++j){
      int nl = nt*128 + w*32 + j*16 + lr;
      if (nl < 1200){
        int col = seg*1200 + nl;
        int mrow = m0 + i*16 + kg*4;
        #pragma unroll
        for (int r = 0; r < 4; ++r)
          Gm[(long)(mrow+r)*2400 + col] = acc[i][j][r];
      }
    }
}

// ---------------- fused GRU-combine + attention + p_gen (+gates), SG=5 slots / block -------------
__global__ __launch_bounds__(512) void k_attn(
    const float* __restrict__ Eo, const int* __restrict__ cmask,
    const float* __restrict__ Gm, const float* __restrict__ bih, const float* __restrict__ bhh,
    float* __restrict__ Hh, u16* __restrict__ Hbf, const float* __restrict__ X,
    const float* __restrict__ wr, const float* __restrict__ wrb,
    const float* __restrict__ wg, const float* __restrict__ wgb,
    float* __restrict__ cp, float* __restrict__ pgen, float* __restrict__ og, int t)
{
  __shared__ float sh_h[SG][Hd];
  __shared__ float sh_c[SG][Hd];
  __shared__ float sh_p[SG][Ll];
  __shared__ float buf[4*SG*Ll];     // 40KB scratch: score partials / ctx partials / reductions
  int tid = threadIdx.x, b = blockIdx.y, s0 = blockIdx.x*SG;

  // GRU combine for our 5 rows
  for (int idx = tid; idx < SG*Hd; idx += 512){
    int sg = idx / Hd, j = idx - sg*Hd;
    long m = (long)(s0+sg)*B_ + b;
    const float* g = Gm + m*2400;
    float r = 1.f/(1.f+expf(-(g[j]     + bih[j]     + g[1200+j] + bhh[j])));
    float z = 1.f/(1.f+expf(-(g[400+j] + bih[400+j] + g[1600+j] + bhh[400+j])));
    float n = tanhf(g[800+j] + bih[800+j] + r*(g[2000+j] + bhh[800+j]));
    float h = (1.f-z)*n + z*Hh[m*KP + j];
    sh_h[sg][j] = h;
    Hh[m*KP + j] = h;
    Hbf[m*KP + j] = f2bf(h);
  }
  __syncthreads();

  // scores: thread = (lq = tid&127, kq = tid>>7); 4 l's per thread, k in [kq*100, kq*100+100)
  {
    int lq = tid & 127, kq = tid >> 7;
    float sc[4][SG];
    #pragma unroll
    for (int j = 0; j < 4; ++j)
      #pragma unroll
      for (int sg = 0; sg < SG; ++sg) sc[j][sg] = 0.f;
    int k0 = kq*100;
    for (int kk = 0; kk < 100; kk += 4){
      int k = k0 + kk;
      f4 h4[SG];
      #pragma unroll
      for (int sg = 0; sg < SG; ++sg) h4[sg] = *(const f4*)&sh_h[sg][k];
      #pragma unroll
      for (int j = 0; j < 4; ++j){
        f4 e = *(const f4*)&Eo[((long)b*Ll + lq + 128*j)*Hd + k];
        #pragma unroll
        for (int sg = 0; sg < SG; ++sg)
          sc[j][sg] += e.x*h4[sg].x + e.y*h4[sg].y + e.z*h4[sg].z + e.w*h4[sg].w;
      }
    }
    #pragma unroll
    for (int j = 0; j < 4; ++j)
      #pragma unroll
      for (int sg = 0; sg < SG; ++sg)
        buf[(kq*SG+sg)*Ll + lq + 128*j] = sc[j][sg];
  }
  __syncthreads();

  // combine partials + masked softmax (thread = l)
  float v[SG];
  {
    bool mok = cmask[b*Ll + tid] != 0;
    #pragma unroll
    for (int sg = 0; sg < SG; ++sg){
      float x = buf[sg*Ll+tid] + buf[(SG+sg)*Ll+tid] + buf[(2*SG+sg)*Ll+tid] + buf[(3*SG+sg)*Ll+tid];
      v[sg] = mok ? x : -INF;
    }
  }
  __syncthreads();
  #pragma unroll
  for (int sg = 0; sg < SG; ++sg) buf[sg*Ll + tid] = v[sg];
  __syncthreads();
  for (int o = 256; o > 0; o >>= 1){
    if (tid < o){
      #pragma unroll
      for (int sg = 0; sg < SG; ++sg)
        buf[sg*Ll+tid] = fmaxf(buf[sg*Ll+tid], buf[sg*Ll+tid+o]);
    }
    __syncthreads();
  }
  float mx[SG];
  #pragma unroll
  for (int sg = 0; sg < SG; ++sg) mx[sg] = buf[sg*Ll];
  __syncthreads();
  float p[SG];
  #pragma unroll
  for (int sg = 0; sg < SG; ++sg){ p[sg] = expf(v[sg]-mx[sg]); buf[sg*Ll+tid] = p[sg]; }
  __syncthreads();
  for (int o = 256; o > 0; o >>= 1){
    if (tid < o){
      #pragma unroll
      for (int sg = 0; sg < SG; ++sg) buf[sg*Ll+tid] += buf[sg*Ll+tid+o];
    }
    __syncthreads();
  }
  #pragma unroll
  for (int sg = 0; sg < SG; ++sg){
    float pp = p[sg] / buf[sg*Ll];
    sh_p[sg][tid] = pp;
    cp[((long)(s0+sg)*B_ + b)*Ll + tid] = pp;
  }
  __syncthreads();

  // ctx: thread = (k4 = tid&127 [<100 active], lq = tid>>7); ctx[sg][k4*4..+3] partial over 128 l's
  {
    int k4 = tid & 127, lq = tid >> 7;
    if (k4 < 100){
      int k = k4*4;
      f4 cacc[SG];
      #pragma unroll
      for (int sg = 0; sg < SG; ++sg) cacc[sg] = f4{0.f,0.f,0.f,0.f};
      for (int li = 0; li < 128; li += 4){
        int l = lq*128 + li;
        f4 pv[SG];
        #pragma unroll
        for (int sg = 0; sg < SG; ++sg) pv[sg] = *(const f4*)&sh_p[sg][l];
        #pragma unroll
        for (int jj = 0; jj < 4; ++jj){
          f4 e = *(const f4*)&Eo[((long)b*Ll + l + jj)*Hd + k];
          #pragma unroll
          for (int sg = 0; sg < SG; ++sg){
            float pw = pv[sg][jj];
            cacc[sg].x += e.x*pw; cacc[sg].y += e.y*pw; cacc[sg].z += e.z*pw; cacc[sg].w += e.w*pw;
          }
        }
      }
      #pragma unroll
      for (int sg = 0; sg < SG; ++sg)
        *(f4*)&buf[(lq*SG+sg)*Hd + k] = cacc[sg];
    }
  }
  __syncthreads();
  if (tid < Hd){
    #pragma unroll
    for (int sg = 0; sg < SG; ++sg)
      sh_c[sg][tid] = buf[sg*Hd+tid] + buf[(SG+sg)*Hd+tid] + buf[(2*SG+sg)*Hd+tid] + buf[(3*SG+sg)*Hd+tid];
  }
  __syncthreads();

  // p_gen = sigmoid([h,c,x].wr + b), all 5 sg in parallel
  {
    float part[SG] = {0,0,0,0,0};
    for (int j = tid; j < 1200; j += 512){
      float wv = wr[j];
      #pragma unroll
      for (int sg = 0; sg < SG; ++sg){
        float xv;
        if (j < 400) xv = sh_h[sg][j];
        else if (j < 800) xv = sh_c[sg][j-400];
        else xv = X[((long)(s0+sg)*B_ + b)*KP + (j-800)];
        part[sg] += xv*wv;
      }
    }
    #pragma unroll
    for (int sg = 0; sg < SG; ++sg) buf[sg*Ll + tid] = part[sg];
    __syncthreads();
    for (int o = 256; o > 0; o >>= 1){
      if (tid < o){
        #pragma unroll
        for (int sg = 0; sg < SG; ++sg) buf[sg*Ll+tid] += buf[sg*Ll+tid+o];
      }
      __syncthreads();
    }
    if (tid < SG)
      pgen[(long)(s0+tid)*B_ + b] = 1.f/(1.f+expf(-(buf[tid*Ll] + wrb[0])));
    __syncthreads();
  }

  // gates logits at t==0
  if (t == 0){
    for (int g = 0; g < Gg; ++g){
      float pt[SG] = {0,0,0,0,0};
      if (tid < Hd){
        float wv = wg[g*Hd + tid];
        #pragma unroll
        for (int sg = 0; sg < SG; ++sg) pt[sg] = sh_c[sg][tid]*wv;
      }
      #pragma unroll
      for (int sg = 0; sg < SG; ++sg) buf[sg*Ll + tid] = pt[sg];
      __syncthreads();
      for (int o = 256; o > 0; o >>= 1){
        if (tid < o){
          #pragma unroll
          for (int sg = 0; sg < SG; ++sg) buf[sg*Ll+tid] += buf[sg*Ll+tid+o];
        }
        __syncthreads();
      }
      if (tid < SG) og[((long)b*S_ + (s0+tid))*Gg + g] = buf[tid*Ll] + wgb[g];
      __syncthreads();
    }
  }
}

// ---------------- vocab GEMM: B stripe resident in LDS + fused row max/sumexp partials ----------
// grid (141, 3): x = n-stripe of 128 cols, y = m-third (5 m-tiles of 32 rows)
__global__ __launch_bounds__(256) void k_vgemm(
    const u16* __restrict__ Abf, const u16* __restrict__ Bhi,
    float* __restrict__ Z, float* __restrict__ pmax, float* __restrict__ psum)
{
  __shared__ u16 Bs[128*456];          // 116,736 B
  __shared__ u16 As[32*456];           //  29,184 B
  __shared__ float redm[4][32], reds[4][32];
  int tid = threadIdx.x;
  int ns = blockIdx.x, third = blockIdx.y;
  long brow0 = (long)ns*128;
  for (int i = 0; i < 28; ++i){
    int idx = i*256 + tid;
    int row = idx / 56, c = idx - row*56;
    *(uint4*)&Bs[row*456 + c*8] = *(const uint4*)(Bhi + (brow0+row)*KP + c*8);
  }
  int w = tid>>6, l = tid&63, lr = l&15, kg = l>>4;
  int col0 = (int)brow0 + w*32 + lr;
  bool v0 = col0 < Vv, v1 = (col0+16) < Vv;
  for (int mt = third*5; mt < third*5+5; ++mt){
    __syncthreads();
    for (int i = 0; i < 7; ++i){
      int idx = i*256 + tid;
      int row = idx / 56, c = idx - row*56;
      *(uint4*)&As[row*456 + c*8] = *(const uint4*)(Abf + (long)(mt*32+row)*KP + c*8);
    }
    __syncthreads();
    f4 acc[2][2] = {};
    for (int ks = 0; ks < 14; ++ks){
      int kb = ks*32 + kg*8;
      bf8 a0 = *(const bf8*)&As[lr*456 + kb];
      bf8 a1 = *(const bf8*)&As[(16+lr)*456 + kb];
      bf8 b0 = *(const bf8*)&Bs[(w*32+lr)*456 + kb];
      bf8 b1 = *(const bf8*)&Bs[(w*32+16+lr)*456 + kb];
      acc[0][0] = __builtin_amdgcn_mfma_f32_16x16x32_bf16(a0,b0,acc[0][0],0,0,0);
      acc[0][1] = __builtin_amdgcn_mfma_f32_16x16x32_bf16(a0,b1,acc[0][1],0,0,0);
      acc[1][0] = __builtin_amdgcn_mfma_f32_16x16x32_bf16(a1,b0,acc[1][0],0,0,0);
      acc[1][1] = __builtin_amdgcn_mfma_f32_16x16x32_bf16(a1,b1,acc[1][1],0,0,0);
    }
    #pragma unroll
    for (int i = 0; i < 2; ++i){
      int rbase = mt*32 + i*16 + kg*4;
      #pragma unroll
      for (int r = 0; r < 4; ++r){
        long zrow = (long)(rbase + r)*Vv;
        if (v0) Z[zrow + col0]      = acc[i][0][r];
        if (v1) Z[zrow + col0 + 16] = acc[i][1][r];
        float x0 = v0 ? acc[i][0][r] : -INF;
        float x1 = v1 ? acc[i][1][r] : -INF;
        float mxv = fmaxf(x0, x1);
        #pragma unroll
        for (int d = 1; d < 16; d <<= 1) mxv = fmaxf(mxv, __shfl_xor(mxv, d));
        float s = (v0 ? expf(x0-mxv) : 0.f) + (v1 ? expf(x1-mxv) : 0.f);
        #pragma unroll
        for (int d = 1; d < 16; d <<= 1) s += __shfl_xor(s, d);
        if (lr == 0){ redm[w][i*16+kg*4+r] = mxv; reds[w][i*16+kg*4+r] = s; }
      }
    }
    __syncthreads();
    if (tid < 32){
      float gm = fmaxf(fmaxf(redm[0][tid],redm[1][tid]), fmaxf(redm[2][tid],redm[3][tid]));
      float gs = 0.f;
      #pragma unroll
      for (int ww = 0; ww < 4; ++ww) gs += reds[ww][tid] * expf(redm[ww][tid] - gm);
      pmax[(long)(mt*32+tid)*NST + ns] = gm;
      psum[(long)(mt*32+tid)*NST + ns] = gs;
    }
  }
}

// ---------------- fused: partial-combine + finalize + scatter + argmax + greedy feedback --------
__global__ __launch_bounds__(512) void k_final(
    const float* __restrict__ Z, const float* __restrict__ pmax, const float* __restrict__ psum,
    const float* __restrict__ pgen, const float* __restrict__ cp,
    const int* __restrict__ cidx, const int* __restrict__ cmask,
    const float* __restrict__ emb, float* __restrict__ out, float* __restrict__ X, int t)
{
  __shared__ float scat[Vv];           // 72,000 B
  __shared__ float rv[512];
  __shared__ int   ri[512];
  __shared__ float am[256], asum[256];
  int tid = threadIdx.x, m = blockIdx.x;
  int b = m & 15, s = m >> 4;
  if (tid < 256){
    am[tid]   = tid < NST ? pmax[(long)m*NST + tid] : -INF;
    asum[tid] = tid < NST ? psum[(long)m*NST + tid] : 0.f;
  }
  for (int i = tid; i < Vv; i += 512) scat[i] = 0.f;
  __syncthreads();
  for (int o = 128; o > 0; o >>= 1){
    if (tid < o){
      float m2 = am[tid+o], M = fmaxf(am[tid], m2);
      asum[tid] = asum[tid]*expf(am[tid]-M) + asum[tid+o]*expf(m2-M);
      am[tid] = M;
    }
    __syncthreads();
  }
  float gmx = am[0], pg = pgen[m], inv = 1.f/asum[0];
  // scatter copy distribution (LDS atomics)
  if (cmask[b*Ll + tid]){
    float vv = (1.f - pg)*cp[(long)m*Ll + tid];
    atomicAdd(&scat[cidx[b*Ll + tid]], vv);
  }
  __syncthreads();
  long zb = (long)m*Vv;
  long ob = ((long)(b*S_ + s)*Tt + t)*(long)Vv;
  float bv = -1.f; int bi = 0;
  float sc0 = pg*inv;
  for (int i = tid; i < Vv/4; i += 512){
    f4 z = *(const f4*)&Z[zb + i*4];
    f4 sc4 = *(const f4*)&scat[i*4];
    f4 o;
    o.x = sc0*expf(z.x - gmx) + sc4.x;
    o.y = sc0*expf(z.y - gmx) + sc4.y;
    o.z = sc0*expf(z.z - gmx) + sc4.z;
    o.w = sc0*expf(z.w - gmx) + sc4.w;
    *(f4*)&out[ob + i*4] = o;
    int n0 = i*4;
    if (o.x > bv){ bv = o.x; bi = n0; }
    if (o.y > bv){ bv = o.y; bi = n0+1; }
    if (o.z > bv){ bv = o.z; bi = n0+2; }
    if (o.w > bv){ bv = o.w; bi = n0+3; }
  }
  rv[tid] = bv; ri[tid] = bi;
  __syncthreads();
  for (int o = 256; o > 0; o >>= 1){
    if (tid < o){
      float v2 = rv[tid+o]; int i2 = ri[tid+o];
      if (v2 > rv[tid] || (v2 == rv[tid] && i2 < ri[tid])){ rv[tid] = v2; ri[tid] = i2; }
    }
    __syncthreads();
  }
  int win = ri[0];
  if (tid < Hd) X[(long)m*KP + tid] = emb[(long)win*Hd + tid];
}

// ---------------- launcher ----------------
extern "C" void kernel_launch(void* const* d_in, const int* in_sizes, int n_in,
                              void* d_out, int out_size, void* d_ws, size_t ws_size,
                              hipStream_t stream)
{
  const float* ehid  = (const float*)d_in[0];
  const float* eout  = (const float*)d_in[1];
  const int*   cidx  = (const int*)d_in[2];
  const int*   cmask = (const int*)d_in[3];
  const float* emb   = (const float*)d_in[5];
  const float* semb  = (const float*)d_in[6];
  const int*   didx  = (const int*)d_in[7];
  const int*   sidx  = (const int*)d_in[8];
  const float* Wih   = (const float*)d_in[9];
  const float* Whh   = (const float*)d_in[10];
  const float* bih   = (const float*)d_in[11];
  const float* bhh   = (const float*)d_in[12];
  const float* wr    = (const float*)d_in[13];
  const float* wrb   = (const float*)d_in[14];
  const float* wg    = (const float*)d_in[15];
  const float* wgb   = (const float*)d_in[16];
  float* out = (float*)d_out;

  char* ws = (char*)d_ws;
  u16*   ws_hi = (u16*)(ws + 0);            //  2,293,760
  u16*   ws_lo = (u16*)(ws + 2293760);      //  2,293,760
  u16*   ebf   = (u16*)(ws + 4587520);      // 16,285,696
  float* X     = (float*)(ws + 20873216);   //    860,160
  float* Hh    = (float*)(ws + 21733376);   //    860,160
  u16*   Hbf   = (u16*)(ws + 22593536);     //    430,080
  float* Gm    = (float*)(ws + 23023616);   //  4,608,000
  float* Z     = (float*)(ws + 27631616);   // 34,560,000
  float* cp    = (float*)(ws + 62191616);   //    983,040
  float* pg    = (float*)(ws + 63174656);   //      2,048
  float* pmax  = (float*)(ws + 63176704);   //    270,848
  float* psum  = (float*)(ws + 63447552);   //    270,848
  float* og = out + (long)B_*S_*Tt*Vv;

  k_setup_w <<<4480, 256, 0, stream>>>(Wih, Whh, ws_hi, ws_lo);
  k_setup_e <<<4096, 256, 0, stream>>>(emb, ebf);
  k_setup_xh<<<480, 448, 0, stream>>>(ehid, semb, didx, sidx, X, Hh, Hbf);

  for (int t = 0; t < Tt; ++t){
    k_ggemm <<<dim3(15,20), 256, 0, stream>>>(X, Hh, ws_hi, ws_lo, Gm);
    k_attn  <<<dim3(6,16), 512, 0, stream>>>(eout, cmask, Gm, bih, bhh, Hh, Hbf, X,
                                             wr, wrb, wg, wgb, cp, pg, og, t);
    k_vgemm <<<dim3(141,3), 256, 0, stream>>>(Hbf, ebf, Z, pmax, psum);
    k_final <<<480, 512, 0, stream>>>(Z, pmax, psum, pg, cp, cidx, cmask, emb, out, X, t);
  }
}